// Round 1
// baseline (1190.264 us; speedup 1.0000x reference)
//
#include <hip/hip_runtime.h>

#define EPS 1e-3f

// ---------------------------------------------------------------------------
// Kernel 1: fused 1x1-conv (C -> K*F) + graph contraction over A[k,t,:,:]
//           + BN1 + ReLU.  One block per (n, t).
// Writes h in layout [n][t][f][w]  (1600 contiguous floats per (n,t)).
// ---------------------------------------------------------------------------
__global__ __launch_bounds__(256) void k1_gcn(
    const float* __restrict__ x,      // [64,64,300,25]
    const float* __restrict__ W1,     // [64,192]
    const float* __restrict__ b1,     // [192]
    const float* __restrict__ A,      // [3,300,25,25]
    const float* __restrict__ gamma1, const float* __restrict__ beta1,
    const float* __restrict__ mean1,  const float* __restrict__ var1,
    float* __restrict__ h)            // ws: [64][300][64][25]
{
    const int t   = blockIdx.x;
    const int n   = blockIdx.y;
    const int tid = threadIdx.x;

    __shared__ float xs [64 * 28];      // [c][v], stride 28 (16B-aligned rows)
    __shared__ float AsT[3 * 25 * 28];  // [k][w][v], stride 28
    __shared__ float ys [192 * 28];     // [j][v],   stride 28

    // ---- stage x[n,:,t,:] ----
    for (int i = tid; i < 64 * 25; i += 256) {
        int c = i / 25, v = i % 25;
        xs[c * 28 + v] = x[((n * 64 + c) * 300 + t) * 25 + v];
    }
    // ---- stage A[:,t,:,:] transposed to [k][w][v] ----
    for (int i = tid; i < 3 * 25 * 25; i += 256) {
        int k = i / 625, r = i % 625, v = r / 25, w = r % 25;
        AsT[k * 700 + w * 28 + v] = A[(k * 300 + t) * 625 + v * 25 + w];
    }
    __syncthreads();

    // ---- phase 1: ys[j][v] = b1[j] + sum_c W1[c][j] * xs[c][v] ----
    if (tid < 192) {
        const int j = tid;
        float acc[25];
        const float bj = b1[j];
        #pragma unroll
        for (int v = 0; v < 25; ++v) acc[v] = bj;
        for (int c = 0; c < 64; ++c) {
            const float wv = W1[c * 192 + j];
            #pragma unroll
            for (int v = 0; v < 25; ++v)
                acc[v] = fmaf(wv, xs[c * 28 + v], acc[v]);
        }
        #pragma unroll
        for (int v = 0; v < 25; ++v) ys[j * 28 + v] = acc[v];
    }
    __syncthreads();

    // ---- phase 2: z[f][w] = sum_k sum_v ys[k*64+f][v] * AsT[k][w][v];
    //      BN1 + ReLU; coalesced store ----
    for (int i = tid; i < 1600; i += 256) {
        const int f = i / 25, w = i % 25;
        float z = 0.f;
        #pragma unroll
        for (int k = 0; k < 3; ++k) {
            const float* __restrict__ yrow = &ys[(k * 64 + f) * 28];
            const float* __restrict__ arow = &AsT[k * 700 + w * 28];
            #pragma unroll
            for (int v = 0; v < 25; ++v)
                z = fmaf(yrow[v], arow[v], z);
        }
        const float rs = rsqrtf(var1[f] + EPS);
        const float s  = gamma1[f] * rs;
        const float b  = beta1[f] - gamma1[f] * mean1[f] * rs;
        h[(n * 300 + t) * 1600 + i] = fmaxf(fmaf(z, s, b), 0.f);
    }
}

// ---------------------------------------------------------------------------
// Kernel 2: temporal conv [9,1] SAME over T + bias + BN2 + residual + ReLU.
// One block per (n, 8-wide t-tile). fi processed in 2 chunks of 32 via LDS.
// Thread (f = tid&63, g = tid>>6) owns w-group of <=7 columns, all 8 t's.
// ---------------------------------------------------------------------------
__global__ __launch_bounds__(256) void k2_tcn(
    const float* __restrict__ h,      // ws layout [n][t][f][w]
    const float* __restrict__ Wt,     // [9,1,64,64]  (dt, fi, fo)
    const float* __restrict__ bt,     // [64]
    const float* __restrict__ gamma2, const float* __restrict__ beta2,
    const float* __restrict__ mean2,  const float* __restrict__ var2,
    const float* __restrict__ x,      // [64,64,300,25] residual
    float* __restrict__ out)          // [64,64,300,25]
{
    const int tt0 = blockIdx.x * 8;
    const int n   = blockIdx.y;
    const int tid = threadIdx.x;
    const int f   = tid & 63;
    const int g   = tid >> 6;

    // chunk buffer [fi(32)][tt(16)][w(25)] = 12800 floats; epilogue staging
    // reuses it as [f(64)][201] (pad 201 kills the stride-200 bank conflict).
    __shared__ float hs[12864];

    const int w0tab[4] = {0, 7, 13, 19};
    const int wntab[4] = {7, 6, 6, 6};
    const int w0 = w0tab[g];
    const int wn = wntab[g];

    float acc[8][7];
    #pragma unroll
    for (int t = 0; t < 8; ++t)
        #pragma unroll
        for (int wl = 0; wl < 7; ++wl) acc[t][wl] = 0.f;

    for (int c = 0; c < 2; ++c) {
        // ---- stage h[n, tt0-4 .. tt0+11, 32c..32c+31, :] ----
        for (int i = tid; i < 12800; i += 256) {
            int tt = i / 800, r = i % 800, fl = r / 25, w = r % 25;
            int tg = tt0 + tt - 4;
            float v = 0.f;
            if (tg >= 0 && tg < 300)
                v = h[(n * 300 + tg) * 1600 + (c * 32 + fl) * 25 + w];
            hs[fl * 400 + tt * 25 + w] = v;
        }
        __syncthreads();

        for (int fi = 0; fi < 32; ++fi) {
            float wv[9];
            #pragma unroll
            for (int dt = 0; dt < 9; ++dt)
                wv[dt] = Wt[(dt * 64 + c * 32 + fi) * 64 + f];

            #pragma unroll
            for (int tt = 0; tt < 16; ++tt) {
                float hreg[7];
                #pragma unroll
                for (int wl = 0; wl < 7; ++wl)       // unconditional: col 25
                    hreg[wl] = hs[fi * 400 + tt * 25 + w0 + wl]; // bleed unused
                #pragma unroll
                for (int dt = 0; dt < 9; ++dt) {
                    const int t = tt - dt;           // compile-time resolved
                    if (t >= 0 && t < 8) {
                        #pragma unroll
                        for (int wl = 0; wl < 7; ++wl)
                            acc[t][wl] = fmaf(wv[dt], hreg[wl], acc[t][wl]);
                    }
                }
            }
        }
        __syncthreads();
    }

    // ---- stage result to LDS as [f][t*25+w] (stride 201) ----
    #pragma unroll
    for (int t = 0; t < 8; ++t)
        #pragma unroll
        for (int wl = 0; wl < 7; ++wl)
            if (wl < wn) hs[f * 201 + t * 25 + w0 + wl] = acc[t][wl];
    __syncthreads();

    // ---- epilogue: bias + BN2 + residual + ReLU, coalesced ----
    for (int i = tid; i < 12800; i += 256) {
        const int fo = i / 200, r = i % 200;
        const int tg = tt0 + r / 25;
        if (tg < 300) {
            const float rs = rsqrtf(var2[fo] + EPS);
            const float s  = gamma2[fo] * rs;
            const float b  = beta2[fo] - gamma2[fo] * mean2[fo] * rs;
            const float conv = hs[fo * 201 + r] + bt[fo];
            const int gaddr = n * 480000 + fo * 7500 + tt0 * 25 + r;
            out[gaddr] = fmaxf(fmaf(conv, s, b) + x[gaddr], 0.f);
        }
    }
}

// ---------------------------------------------------------------------------
extern "C" void kernel_launch(void* const* d_in, const int* in_sizes, int n_in,
                              void* d_out, int out_size, void* d_ws, size_t ws_size,
                              hipStream_t stream) {
    const float* x      = (const float*)d_in[0];
    const float* W1     = (const float*)d_in[1];
    const float* b1     = (const float*)d_in[2];
    const float* A      = (const float*)d_in[3];
    const float* gamma1 = (const float*)d_in[4];
    const float* beta1  = (const float*)d_in[5];
    const float* mean1  = (const float*)d_in[6];
    const float* var1   = (const float*)d_in[7];
    const float* Wt     = (const float*)d_in[8];
    const float* bt     = (const float*)d_in[9];
    const float* gamma2 = (const float*)d_in[10];
    const float* beta2  = (const float*)d_in[11];
    const float* mean2  = (const float*)d_in[12];
    const float* var2   = (const float*)d_in[13];
    float* out = (float*)d_out;
    float* h   = (float*)d_ws;   // needs 64*300*64*25*4 = 122.88 MB

    k1_gcn<<<dim3(300, 64), 256, 0, stream>>>(
        x, W1, b1, A, gamma1, beta1, mean1, var1, h);
    k2_tcn<<<dim3(38, 64), 256, 0, stream>>>(
        h, Wt, bt, gamma2, beta2, mean2, var2, x, out);
}

// Round 2
// 781.369 us; speedup vs baseline: 1.5233x; 1.5233x over previous
//
#include <hip/hip_runtime.h>
#include <hip/hip_bf16.h>
#include <stdint.h>

#define EPS 1e-3f

typedef __attribute__((ext_vector_type(8))) short bf16x8;
typedef __attribute__((ext_vector_type(4))) float f32x4;

// ---------------------------------------------------------------------------
// Kernel 0: transpose Wt [9][1][fi=64][fo=64] fp32 -> A-operand bf16 layout
//           Abf[(kb*64+fo)*8 + j] where k = kb*8+j = dt*64+fi.
// ---------------------------------------------------------------------------
__global__ __launch_bounds__(256) void k0_wt(const float* __restrict__ Wt,
                                             uint16_t* __restrict__ Abf)
{
    int idx = blockIdx.x * 256 + threadIdx.x;
    if (idx < 36864) {
        int j  = idx & 7;
        int fo = (idx >> 3) & 63;
        int kb = idx >> 9;
        int k  = kb * 8 + j;
        int dt = k >> 6, fi = k & 63;
        __hip_bfloat16 b = __float2bfloat16(Wt[(dt * 64 + fi) * 64 + fo]);
        Abf[idx] = *(uint16_t*)&b;
    }
}

// ---------------------------------------------------------------------------
// Kernel 1: fused 1x1-conv (C -> K*F) + graph contraction + BN1 + ReLU.
// One block per (n, t). Writes h2 as bf16 in layout [n][t][w][f].
// ---------------------------------------------------------------------------
__global__ __launch_bounds__(256) void k1_gcn(
    const float* __restrict__ x,      // [64,64,300,25]
    const float* __restrict__ W1,     // [64,192]
    const float* __restrict__ b1,     // [192]
    const float* __restrict__ A,      // [3,300,25,25]
    const float* __restrict__ gamma1, const float* __restrict__ beta1,
    const float* __restrict__ mean1,  const float* __restrict__ var1,
    uint32_t* __restrict__ h2u)       // ws: [64][300][25][64] bf16, as uints
{
    const int t   = blockIdx.x;
    const int n   = blockIdx.y;
    const int tid = threadIdx.x;

    __shared__ float xs [64 * 28];      // [c][v]; reused as zs after phase 1
    __shared__ float AsT[3 * 25 * 28];  // [k][w][v]
    __shared__ float ys [192 * 28];     // [j][v]
    float* zs = xs;                     // 1600 floats needed, 1792 available

    // ---- stage x[n,:,t,:] ----
    for (int i = tid; i < 64 * 25; i += 256) {
        int c = i / 25, v = i % 25;
        xs[c * 28 + v] = x[((n * 64 + c) * 300 + t) * 25 + v];
    }
    // ---- stage A[:,t,:,:] transposed to [k][w][v] ----
    for (int i = tid; i < 3 * 25 * 25; i += 256) {
        int k = i / 625, r = i % 625, v = r / 25, w = r % 25;
        AsT[k * 700 + w * 28 + v] = A[(k * 300 + t) * 625 + v * 25 + w];
    }
    __syncthreads();

    // ---- phase 1: ys[j][v] = b1[j] + sum_c W1[c][j] * xs[c][v] ----
    if (tid < 192) {
        const int j = tid;
        float acc[25];
        const float bj = b1[j];
        #pragma unroll
        for (int v = 0; v < 25; ++v) acc[v] = bj;
        for (int c = 0; c < 64; ++c) {
            const float wv = W1[c * 192 + j];
            #pragma unroll
            for (int v = 0; v < 25; ++v)
                acc[v] = fmaf(wv, xs[c * 28 + v], acc[v]);
        }
        #pragma unroll
        for (int v = 0; v < 25; ++v) ys[j * 28 + v] = acc[v];
    }
    __syncthreads();

    // ---- phase 2: z[f][w]; BN1 + ReLU; stage to zs (swizzled [w][f]) ----
    for (int i = tid; i < 1600; i += 256) {
        const int f = i / 25, w = i % 25;
        float z = 0.f;
        #pragma unroll
        for (int k = 0; k < 3; ++k) {
            const float* __restrict__ yrow = &ys[(k * 64 + f) * 28];
            const float* __restrict__ arow = &AsT[k * 700 + w * 28];
            #pragma unroll
            for (int v = 0; v < 25; ++v)
                z = fmaf(yrow[v], arow[v], z);
        }
        const float rs = rsqrtf(var1[f] + EPS);
        const float s  = gamma1[f] * rs;
        const float b  = beta1[f] - gamma1[f] * mean1[f] * rs;
        zs[(w << 6) + ((f + w) & 63)] = fmaxf(fmaf(z, s, b), 0.f);
    }
    __syncthreads();

    // ---- pack to bf16 pairs, coalesced store: h2[(n,t)] = 800 uints ----
    const size_t base = (size_t)(n * 300 + t) * 800;
    for (int i = tid; i < 800; i += 256) {
        int j0 = i << 1;
        int w = j0 >> 6, f0 = j0 & 63;
        float v0 = zs[(w << 6) + ((f0 + w) & 63)];
        float v1 = zs[(w << 6) + ((f0 + 1 + w) & 63)];
        __hip_bfloat162 p;
        p.x = __float2bfloat16(v0);
        p.y = __float2bfloat16(v1);
        h2u[base + i] = *(uint32_t*)&p;
    }
}

// ---------------------------------------------------------------------------
// Kernel 2: temporal conv as MFMA GEMM: M=64 (fo), K=576 (dt*64+fi),
//           N = 400 cols (16 t x 25 w) per block. + bias + BN2 + residual +
//           ReLU fused epilogue. One block (4 waves) per (n, t-tile).
// ---------------------------------------------------------------------------
#define K2_SMEM 151040
__global__ __launch_bounds__(256) void k2_mfma(
    const char* __restrict__ h2b,     // bf16 bytes [n][t][w][f]
    const char* __restrict__ Abf,     // bf16 bytes, k0 layout
    const float* __restrict__ bt,
    const float* __restrict__ gamma2, const float* __restrict__ beta2,
    const float* __restrict__ mean2,  const float* __restrict__ var2,
    const float* __restrict__ x,      // [64,64,300,25] residual
    float* __restrict__ out)          // [64,64,300,25]
{
    extern __shared__ __align__(16) char smem[];
    char*  lds_a = smem;               // 73728 B : A [kb(72)][fo(64)][8] bf16
    char*  lds_h = smem + 73728;       // 76800 B : h [(t,w) row(600)][f(64)] bf16
    float* s2s   = (float*)(smem + 150528);
    float* b2s   = s2s + 64;

    const int t0  = blockIdx.x * 16;
    const int n   = blockIdx.y;
    const int tid = threadIdx.x;

    // BN2 constants (BN over conv+bias folded: z*s2 + (bt*s2 + b2))
    if (tid < 64) {
        float rs = rsqrtf(var2[tid] + EPS);
        float s  = gamma2[tid] * rs;
        s2s[tid] = s;
        b2s[tid] = beta2[tid] - gamma2[tid] * mean2[tid] * rs + bt[tid] * s;
    }

    // ---- stage A (linear global -> swizzled LDS) ----
    for (int c = tid; c < 4608; c += 256) {
        int s = c << 4;
        int4 v = *(const int4*)(Abf + s);
        *(int4*)(lds_a + (s ^ (((s >> 10) & 3) << 8))) = v;
    }
    // ---- stage h tile: rows rr = trow*25+w, trow in [0,24), tg = t0-4+trow ----
    const size_t hn = (size_t)n * 300 * 3200;
    for (int c = tid; c < 4800; c += 256) {
        int rr = c >> 3, c8 = c & 7;
        int trow = rr / 25;
        int w = rr - trow * 25;
        int tg = t0 - 4 + trow;
        int4 v = make_int4(0, 0, 0, 0);
        if (tg >= 0 && tg < 300)
            v = *(const int4*)(h2b + hn + (size_t)tg * 3200 + w * 128 + (c8 << 4));
        int s = c << 4;
        *(int4*)(lds_h + (s ^ (((s >> 7) & 7) << 4))) = v;
    }
    __syncthreads();

    const int wv = tid >> 6, lane = tid & 63;
    const int l15 = lane & 15, g = lane >> 4;
    const int colbase = wv * 112;             // waves 0-2: 7 frags, wave 3: 4
    const int nfr = (wv == 3) ? 4 : 7;

    f32x4 acc[4][7];
    #pragma unroll
    for (int mf = 0; mf < 4; ++mf)
        #pragma unroll
        for (int nf = 0; nf < 7; ++nf)
            acc[mf][nf] = (f32x4){0.f, 0.f, 0.f, 0.f};

    for (int kk = 0; kk < 18; ++kk) {
        const int dt   = kk >> 1;
        const int half = (kk & 1) << 6;
        const int kb   = kk * 4 + g;
        bf16x8 a[4];
        #pragma unroll
        for (int mf = 0; mf < 4; ++mf) {
            int s = (kb << 10) + ((l15 + (mf << 4)) << 4);
            a[mf] = *(const bf16x8*)(lds_a + (s ^ ((kb & 3) << 8)));
        }
        #pragma unroll
        for (int nf = 0; nf < 7; ++nf) {
            if (nf < nfr) {
                int r = colbase + (nf << 4) + l15 + 25 * dt;
                int s = (r << 7) + half + (g << 4);
                bf16x8 b = *(const bf16x8*)(lds_h + (s ^ ((r & 7) << 4)));
                acc[0][nf] = __builtin_amdgcn_mfma_f32_16x16x32_bf16(a[0], b, acc[0][nf], 0, 0, 0);
                acc[1][nf] = __builtin_amdgcn_mfma_f32_16x16x32_bf16(a[1], b, acc[1][nf], 0, 0, 0);
                acc[2][nf] = __builtin_amdgcn_mfma_f32_16x16x32_bf16(a[2], b, acc[2][nf], 0, 0, 0);
                acc[3][nf] = __builtin_amdgcn_mfma_f32_16x16x32_bf16(a[3], b, acc[3][nf], 0, 0, 0);
            }
        }
    }

    // ---- epilogue: C row = fo = mf*16 + g*4 + reg; col -> gcol = t*25+w ----
    const size_t outn = (size_t)n * 480000;
    #pragma unroll
    for (int mf = 0; mf < 4; ++mf) {
        #pragma unroll
        for (int nf = 0; nf < 7; ++nf) {
            if (nf < nfr) {
                int col  = colbase + (nf << 4) + l15;
                int gcol = t0 * 25 + col;
                if (gcol < 7500) {
                    #pragma unroll
                    for (int reg = 0; reg < 4; ++reg) {
                        int fo = (mf << 4) + (g << 2) + reg;
                        size_t ga = outn + (size_t)fo * 7500 + gcol;
                        float val = acc[mf][nf][reg] * s2s[fo] + b2s[fo];
                        out[ga] = fmaxf(val + x[ga], 0.f);
                    }
                }
            }
        }
    }
}

// ---------------------------------------------------------------------------
extern "C" void kernel_launch(void* const* d_in, const int* in_sizes, int n_in,
                              void* d_out, int out_size, void* d_ws, size_t ws_size,
                              hipStream_t stream) {
    const float* x      = (const float*)d_in[0];
    const float* W1     = (const float*)d_in[1];
    const float* b1     = (const float*)d_in[2];
    const float* A      = (const float*)d_in[3];
    const float* gamma1 = (const float*)d_in[4];
    const float* beta1  = (const float*)d_in[5];
    const float* mean1  = (const float*)d_in[6];
    const float* var1   = (const float*)d_in[7];
    const float* Wt     = (const float*)d_in[8];
    const float* bt     = (const float*)d_in[9];
    const float* gamma2 = (const float*)d_in[10];
    const float* beta2  = (const float*)d_in[11];
    const float* mean2  = (const float*)d_in[12];
    const float* var2   = (const float*)d_in[13];
    float* out = (float*)d_out;

    // ws layout: h2 bf16 [64][300][25][64] = 61,440,000 B; then Abf 73,728 B
    uint32_t* h2u = (uint32_t*)d_ws;
    char*     h2b = (char*)d_ws;
    uint16_t* Abf = (uint16_t*)((char*)d_ws + 61440000);

    hipFuncSetAttribute((const void*)k2_mfma,
                        hipFuncAttributeMaxDynamicSharedMemorySize, K2_SMEM);

    k0_wt<<<144, 256, 0, stream>>>(Wt, Abf);
    k1_gcn<<<dim3(300, 64), 256, 0, stream>>>(
        x, W1, b1, A, gamma1, beta1, mean1, var1, h2u);
    k2_mfma<<<dim3(19, 64), 256, K2_SMEM, stream>>>(
        h2b, (const char*)Abf, bt, gamma2, beta2, mean2, var2, x, out);
}

// Round 3
// 452.506 us; speedup vs baseline: 2.6304x; 1.7268x over previous
//
#include <hip/hip_runtime.h>
#include <hip/hip_bf16.h>
#include <stdint.h>

#define EPS 1e-3f

typedef __attribute__((ext_vector_type(8))) short bf16x8;
typedef __attribute__((ext_vector_type(4))) float f32x4;

union B8U { bf16x8 v; uint32_t u[4]; };

__device__ inline uint32_t pk2(float a, float b) {
    __hip_bfloat162 p;
    p.x = __float2bfloat16(a);
    p.y = __float2bfloat16(b);
    return *(uint32_t*)&p;
}

// ---------------------------------------------------------------------------
// k0a: small preps.
//  W1t[f][K'] = bf16(W1[c][k*64+f]),  K' = k*64+c           (12288 elems)
//  Abf[(kb*64+fo)*8+j] = bf16(Wt[dt][fi][fo]), kb*8+j=dt*64+fi (36864 elems)
//  csA_g[k][t*25+w] = sum_v A[k][t][v][w]                    (22500 floats)
// ---------------------------------------------------------------------------
__global__ __launch_bounds__(256) void k0_prep_small(
    const float* __restrict__ W1, const float* __restrict__ Wt,
    const float* __restrict__ A,
    uint16_t* __restrict__ W1t, uint16_t* __restrict__ Abf,
    float* __restrict__ csA_g)
{
    int i = blockIdx.x * 256 + threadIdx.x;
    if (i < 12288) {
        int f = i / 192, Kp = i % 192, k = Kp >> 6, c = Kp & 63;
        __hip_bfloat16 b = __float2bfloat16(W1[c * 192 + k * 64 + f]);
        W1t[i] = *(uint16_t*)&b;
    } else if (i < 49152) {
        int j = i - 12288;
        int jj = j & 7, fo = (j >> 3) & 63, kb = j >> 9;
        int kk = kb * 8 + jj, dt = kk >> 6, fi = kk & 63;
        __hip_bfloat16 b = __float2bfloat16(Wt[(dt * 64 + fi) * 64 + fo]);
        Abf[j] = *(uint16_t*)&b;
    } else if (i < 71652) {
        int j = i - 49152;
        int k = j / 7500, r = j % 7500;
        int t = r / 25, w = r % 25;
        float s = 0.f;
        for (int v = 0; v < 25; ++v)
            s += A[((k * 300 + t) * 25 + v) * 25 + w];
        csA_g[j] = s;
    }
}

// ---------------------------------------------------------------------------
// k0b: At_g[k][t][w32][v32] = bf16(A[k][t][v][w]), zero outside v<25,w<25.
// ---------------------------------------------------------------------------
__global__ __launch_bounds__(256) void k0_prep_At(
    const float* __restrict__ A, uint16_t* __restrict__ At_g)
{
    int i = blockIdx.x * 256 + threadIdx.x;
    if (i < 921600) {
        int v = i & 31, w = (i >> 5) & 31, rest = i >> 10;
        int t = rest % 300, k = rest / 300;
        float val = 0.f;
        if (v < 25 && w < 25)
            val = A[((k * 300 + t) * 25 + v) * 25 + w];
        __hip_bfloat16 b = __float2bfloat16(val);
        At_g[i] = *(uint16_t*)&b;
    }
}

// ---------------------------------------------------------------------------
// k1_fused: GEMM-u (x .. A_t) -> U in LDS -> GEMM-z (W1t .. U) -> bias(csA)
//           -> BN1 -> ReLU -> h2 bf16 [n][t][w][f].
// Block = (n, 8-t tile), 4 waves.
// LDS map (bytes): U rows 0..207 x 384 (0..79871); csA 76800..79199;
//                  s1 79200; b1n 79456; b1 79712..80479.  Total 80512.
// ---------------------------------------------------------------------------
#define K1_SMEM 80512
__global__ __launch_bounds__(256) void k1_fused(
    const float* __restrict__ x, const uint16_t* __restrict__ At_g,
    const uint16_t* __restrict__ W1t, const float* __restrict__ csA_g,
    const float* __restrict__ b1,
    const float* __restrict__ gamma1, const float* __restrict__ beta1,
    const float* __restrict__ mean1, const float* __restrict__ var1,
    uint32_t* __restrict__ h2u)
{
    extern __shared__ __align__(16) char smem[];
    float* csA_s = (float*)(smem + 76800);
    float* s1s   = (float*)(smem + 79200);
    float* b1ns  = (float*)(smem + 79456);
    float* b1s   = (float*)(smem + 79712);

    const int t0   = blockIdx.x * 8;
    const int n    = blockIdx.y;
    const int tid  = threadIdx.x;
    const int lane = tid & 63, wv = tid >> 6;
    const int l15  = lane & 15, g = lane >> 4;
    int vc = (300 - t0) * 25; if (vc > 200) vc = 200;
    const int validcols = vc;

    // ---- stage epilogue constants ----
    for (int i = tid; i < 600; i += 256) {
        int k = i / 200, cr = i % 200;
        csA_s[k * 200 + cr] = (cr < validcols) ? csA_g[k * 7500 + t0 * 25 + cr] : 0.f;
    }
    if (tid < 64) {
        float rs = rsqrtf(var1[tid] + EPS);
        s1s[tid]  = gamma1[tid] * rs;
        b1ns[tid] = beta1[tid] - gamma1[tid] * mean1[tid] * rs;
    }
    if (tid >= 64 && tid < 256) b1s[tid - 64] = b1[tid - 64];

    // ---------------- GEMM-u: U[(k,w)-col][K'=k*64+c] over v ----------------
    for (int ti = 0; ti < 2; ++ti) {
        const int trel = wv * 2 + ti;
        const int t = t0 + trel;
        if (t >= 300) continue;

        // A-frags from x (fp32 scalar gather -> bf16); rows c, K = v
        bf16x8 a[4];
        const float* xb = x + (size_t)n * 480000 + t * 25;
        #pragma unroll
        for (int mf = 0; mf < 4; ++mf) {
            const int c = l15 + mf * 16;
            const float* xr = xb + (size_t)c * 7500;
            B8U ua;
            if (g < 3) {
                #pragma unroll
                for (int p = 0; p < 4; ++p)
                    ua.u[p] = pk2(xr[g * 8 + 2 * p], xr[g * 8 + 2 * p + 1]);
            } else {
                ua.u[0] = pk2(xr[24], 0.f);
                ua.u[1] = 0; ua.u[2] = 0; ua.u[3] = 0;
            }
            a[mf] = ua.v;
        }

        f32x4 acc[4][6];
        #pragma unroll
        for (int mf = 0; mf < 4; ++mf)
            #pragma unroll
            for (int nf = 0; nf < 6; ++nf)
                acc[mf][nf] = (f32x4){0.f, 0.f, 0.f, 0.f};

        #pragma unroll
        for (int nf = 0; nf < 6; ++nf) {
            const int col = nf * 16 + l15;
            const int k = col >> 5, w = col & 31;
            bf16x8 b = *(const bf16x8*)(At_g + (((k * 300 + t) * 32 + w) * 32 + g * 8));
            acc[0][nf] = __builtin_amdgcn_mfma_f32_16x16x32_bf16(a[0], b, acc[0][nf], 0, 0, 0);
            acc[1][nf] = __builtin_amdgcn_mfma_f32_16x16x32_bf16(a[1], b, acc[1][nf], 0, 0, 0);
            acc[2][nf] = __builtin_amdgcn_mfma_f32_16x16x32_bf16(a[2], b, acc[2][nf], 0, 0, 0);
            acc[3][nf] = __builtin_amdgcn_mfma_f32_16x16x32_bf16(a[3], b, acc[3][nf], 0, 0, 0);
        }

        // write U to LDS (swizzled), skip padded w
        #pragma unroll
        for (int nf = 0; nf < 6; ++nf) {
            const int col = nf * 16 + l15;
            const int k = col >> 5, w = col & 31;
            if (w < 25) {
                const int colrow = trel * 25 + w;
                const int sw = (w & 7) << 4;
                #pragma unroll
                for (int mf = 0; mf < 4; ++mf) {
                    const int c0 = mf * 16 + g * 4;
                    const int off = colrow * 384 + (((k * 64 + c0) * 2) ^ sw);
                    uint2 val;
                    val.x = pk2(acc[mf][nf][0], acc[mf][nf][1]);
                    val.y = pk2(acc[mf][nf][2], acc[mf][nf][3]);
                    *(uint2*)(smem + off) = val;
                }
            }
        }
    }
    __syncthreads();

    // ---------------- GEMM-z: z[f][col] = W1t * U ----------------
    const int nfbase = (wv == 0) ? 0 : 1 + 3 * wv;   // 0,4,7,10
    const int nfcnt  = (wv == 0) ? 4 : 3;

    int coladdr[4], swz[4], colv[4];
    #pragma unroll
    for (int q = 0; q < 4; ++q) {
        int col = (nfbase + q) * 16 + l15;
        colv[q] = col;
        coladdr[q] = col * 384;
        swz[q] = ((col % 25) & 7) << 4;
    }

    f32x4 accz[4][4];
    #pragma unroll
    for (int mf = 0; mf < 4; ++mf)
        #pragma unroll
        for (int q = 0; q < 4; ++q)
            accz[mf][q] = (f32x4){0.f, 0.f, 0.f, 0.f};

    for (int kb = 0; kb < 6; ++kb) {
        bf16x8 a[4];
        #pragma unroll
        for (int mf = 0; mf < 4; ++mf) {
            int f = l15 + mf * 16;
            a[mf] = *(const bf16x8*)(W1t + f * 192 + kb * 32 + g * 8);
        }
        #pragma unroll
        for (int q = 0; q < 4; ++q) {
            if (q < nfcnt) {
                bf16x8 b = *(const bf16x8*)(smem + coladdr[q] + ((kb * 64 + g * 16) ^ swz[q]));
                accz[0][q] = __builtin_amdgcn_mfma_f32_16x16x32_bf16(a[0], b, accz[0][q], 0, 0, 0);
                accz[1][q] = __builtin_amdgcn_mfma_f32_16x16x32_bf16(a[1], b, accz[1][q], 0, 0, 0);
                accz[2][q] = __builtin_amdgcn_mfma_f32_16x16x32_bf16(a[2], b, accz[2][q], 0, 0, 0);
                accz[3][q] = __builtin_amdgcn_mfma_f32_16x16x32_bf16(a[3], b, accz[3][q], 0, 0, 0);
            }
        }
    }

    // ---- epilogue: +bias(csA), BN1, ReLU, pack bf16, store h2 ----
    const uint32_t hbase = (uint32_t)(n * 300 + t0) * 800;
    #pragma unroll
    for (int q = 0; q < 4; ++q) {
        if (q < nfcnt) {
            const int col = colv[q];
            if (col < validcols) {
                const int trel = col / 25, w = col - trel * 25;
                const float cs0 = csA_s[col];
                const float cs1 = csA_s[200 + col];
                const float cs2 = csA_s[400 + col];
                const uint32_t rowbase = hbase + trel * 800 + w * 32;
                #pragma unroll
                for (int mf = 0; mf < 4; ++mf) {
                    const int f0 = mf * 16 + g * 4;
                    float zz[4];
                    #pragma unroll
                    for (int r = 0; r < 4; ++r) {
                        const int f = f0 + r;
                        float z = accz[mf][q][r]
                                + b1s[f] * cs0 + b1s[64 + f] * cs1 + b1s[128 + f] * cs2;
                        z = z * s1s[f] + b1ns[f];
                        zz[r] = fmaxf(z, 0.f);
                    }
                    uint2 st;
                    st.x = pk2(zz[0], zz[1]);
                    st.y = pk2(zz[2], zz[3]);
                    *(uint2*)(h2u + rowbase + (f0 >> 1)) = st;
                }
            }
        }
    }
}

// ---------------------------------------------------------------------------
// k2: temporal conv MFMA GEMM (M=64 fo, K=576, N=400 cols/block) + bias + BN2
//     + residual + ReLU.  Wt frags direct from global (L2); LDS = h tile only.
// ---------------------------------------------------------------------------
#define K2_SMEM 77312
__global__ __launch_bounds__(256) void k2_mfma(
    const char* __restrict__ h2b,     // bf16 bytes [n][t][w][f]
    const uint16_t* __restrict__ Abf, // Wt bf16, k0 layout
    const float* __restrict__ bt,
    const float* __restrict__ gamma2, const float* __restrict__ beta2,
    const float* __restrict__ mean2,  const float* __restrict__ var2,
    const float* __restrict__ x,      // residual
    float* __restrict__ out)
{
    extern __shared__ __align__(16) char smem2[];
    char*  lds_h = smem2;              // 76800 B
    float* s2s   = (float*)(smem2 + 76800);
    float* b2s   = s2s + 64;

    const int t0  = blockIdx.x * 16;
    const int n   = blockIdx.y;
    const int tid = threadIdx.x;

    if (tid < 64) {
        float rs = rsqrtf(var2[tid] + EPS);
        float s  = gamma2[tid] * rs;
        s2s[tid] = s;
        b2s[tid] = beta2[tid] - gamma2[tid] * mean2[tid] * rs + bt[tid] * s;
    }

    // ---- stage h tile (24 t-rows with halo), swizzled ----
    const size_t hn = (size_t)n * 300 * 3200;
    for (int c = tid; c < 4800; c += 256) {
        int rr = c >> 3, c8 = c & 7;
        int trow = rr / 25;
        int w = rr - trow * 25;
        int tg = t0 - 4 + trow;
        int4 v = make_int4(0, 0, 0, 0);
        if (tg >= 0 && tg < 300)
            v = *(const int4*)(h2b + hn + (size_t)tg * 3200 + w * 128 + (c8 << 4));
        int s = c << 4;
        *(int4*)(lds_h + (s ^ (((s >> 7) & 7) << 4))) = v;
    }
    __syncthreads();

    const int wv = tid >> 6, lane = tid & 63;
    const int l15 = lane & 15, g = lane >> 4;
    const int colbase = wv * 112;
    const int nfr = (wv == 3) ? 4 : 7;

    f32x4 acc[4][7];
    #pragma unroll
    for (int mf = 0; mf < 4; ++mf)
        #pragma unroll
        for (int nf = 0; nf < 7; ++nf)
            acc[mf][nf] = (f32x4){0.f, 0.f, 0.f, 0.f};

    for (int kk = 0; kk < 18; ++kk) {
        const int dt   = kk >> 1;
        const int half = (kk & 1) << 6;
        const int kb   = kk * 4 + g;
        bf16x8 a[4];
        #pragma unroll
        for (int mf = 0; mf < 4; ++mf)
            a[mf] = *(const bf16x8*)(Abf + (kb * 64 + l15 + mf * 16) * 8);
        #pragma unroll
        for (int nf = 0; nf < 7; ++nf) {
            if (nf < nfr) {
                int r = colbase + (nf << 4) + l15 + 25 * dt;
                int s = (r << 7) + half + (g << 4);
                bf16x8 b = *(const bf16x8*)(lds_h + (s ^ ((r & 7) << 4)));
                acc[0][nf] = __builtin_amdgcn_mfma_f32_16x16x32_bf16(a[0], b, acc[0][nf], 0, 0, 0);
                acc[1][nf] = __builtin_amdgcn_mfma_f32_16x16x32_bf16(a[1], b, acc[1][nf], 0, 0, 0);
                acc[2][nf] = __builtin_amdgcn_mfma_f32_16x16x32_bf16(a[2], b, acc[2][nf], 0, 0, 0);
                acc[3][nf] = __builtin_amdgcn_mfma_f32_16x16x32_bf16(a[3], b, acc[3][nf], 0, 0, 0);
            }
        }
    }

    const size_t outn = (size_t)n * 480000;
    #pragma unroll
    for (int mf = 0; mf < 4; ++mf) {
        #pragma unroll
        for (int nf = 0; nf < 7; ++nf) {
            if (nf < nfr) {
                int col  = colbase + (nf << 4) + l15;
                int gcol = t0 * 25 + col;
                if (gcol < 7500) {
                    #pragma unroll
                    for (int reg = 0; reg < 4; ++reg) {
                        int fo = (mf << 4) + (g << 2) + reg;
                        size_t ga = outn + (size_t)fo * 7500 + gcol;
                        float val = acc[mf][nf][reg] * s2s[fo] + b2s[fo];
                        out[ga] = fmaxf(val + x[ga], 0.f);
                    }
                }
            }
        }
    }
}

// ---------------------------------------------------------------------------
extern "C" void kernel_launch(void* const* d_in, const int* in_sizes, int n_in,
                              void* d_out, int out_size, void* d_ws, size_t ws_size,
                              hipStream_t stream) {
    const float* x      = (const float*)d_in[0];
    const float* W1     = (const float*)d_in[1];
    const float* b1     = (const float*)d_in[2];
    const float* A      = (const float*)d_in[3];
    const float* gamma1 = (const float*)d_in[4];
    const float* beta1  = (const float*)d_in[5];
    const float* mean1  = (const float*)d_in[6];
    const float* var1   = (const float*)d_in[7];
    const float* Wt     = (const float*)d_in[8];
    const float* bt     = (const float*)d_in[9];
    const float* gamma2 = (const float*)d_in[10];
    const float* beta2  = (const float*)d_in[11];
    const float* mean2  = (const float*)d_in[12];
    const float* var2   = (const float*)d_in[13];
    float* out = (float*)d_out;

    // ws layout (bytes):
    //   h2   : 0          .. 61,440,000   bf16 [64][300][25][64]
    //   At_g : 61,440,000 .. 63,283,200   bf16 [3][300][32][32]
    //   W1t  : 63,283,200 .. 63,307,776   bf16 [64][192]
    //   Abf  : 63,307,776 .. 63,381,504   bf16 Wt frags
    //   csA_g: 63,381,504 .. 63,471,504   f32  [3][7500]
    char* ws = (char*)d_ws;
    uint32_t* h2u   = (uint32_t*)ws;
    char*     h2b   = ws;
    uint16_t* At_g  = (uint16_t*)(ws + 61440000);
    uint16_t* W1t   = (uint16_t*)(ws + 63283200);
    uint16_t* Abf   = (uint16_t*)(ws + 63307776);
    float*    csA_g = (float*)   (ws + 63381504);

    hipFuncSetAttribute((const void*)k1_fused,
                        hipFuncAttributeMaxDynamicSharedMemorySize, K1_SMEM);
    hipFuncSetAttribute((const void*)k2_mfma,
                        hipFuncAttributeMaxDynamicSharedMemorySize, K2_SMEM);

    k0_prep_small<<<280, 256, 0, stream>>>(W1, Wt, A, W1t, Abf, csA_g);
    k0_prep_At<<<3600, 256, 0, stream>>>(A, At_g);
    k1_fused<<<dim3(38, 64), 256, K1_SMEM, stream>>>(
        x, At_g, W1t, csA_g, b1, gamma1, beta1, mean1, var1, h2u);
    k2_mfma<<<dim3(19, 64), 256, K2_SMEM, stream>>>(
        h2b, Abf, bt, gamma2, beta2, mean2, var2, x, out);
}